// Round 6
// baseline (323.888 us; speedup 1.0000x reference)
//
#include <hip/hip_runtime.h>
#include <hip/hip_bf16.h>

#define N_NODES 50000
#define N_EDGES 800000
#define IN_F    128
#define HID     16
#define HEADS   8
#define F1      128   // HEADS*HID
#define CLS     40
#define NEG     0.2f
#define NEG_INF (-__builtin_inff())

typedef __bf16 bf16x8 __attribute__((ext_vector_type(8)));
typedef float  f32x4  __attribute__((ext_vector_type(4)));

__device__ __forceinline__ float leaky(float v) { return v >= 0.0f ? v : NEG * v; }

// ---------------- CSR build ----------------
__global__ void zero_int_kernel(int* __restrict__ p, int n) {
    int i = blockIdx.x * blockDim.x + threadIdx.x;
    if (i < n) p[i] = 0;
}

__global__ void hist_kernel(const int* __restrict__ dst, int* __restrict__ counts) {
    int e = blockIdx.x * blockDim.x + threadIdx.x;
    if (e < N_EDGES) atomicAdd(&counts[dst[e]], 1);
}

__global__ void reduce_kernel(const int* __restrict__ counts, int* __restrict__ bsum) {
    __shared__ int sm[256];
    int t = threadIdx.x;
    int i = blockIdx.x * 256 + t;
    sm[t] = (i < N_NODES) ? counts[i] : 0;
    __syncthreads();
    for (int off = 128; off > 0; off >>= 1) {
        if (t < off) sm[t] += sm[t + off];
        __syncthreads();
    }
    if (t == 0) bsum[blockIdx.x] = sm[0];
}

__global__ void scanb_kernel(const int* __restrict__ bsum, int* __restrict__ bpref, int nb) {
    __shared__ int sm[256];
    int t = threadIdx.x;
    int x = (t < nb) ? bsum[t] : 0;
    sm[t] = x;
    __syncthreads();
    for (int off = 1; off < 256; off <<= 1) {
        int v = (t >= off) ? sm[t - off] : 0;
        __syncthreads();
        sm[t] += v;
        __syncthreads();
    }
    bpref[t] = sm[t] - x;   // exclusive
}

__global__ void scan_kernel(const int* __restrict__ counts, const int* __restrict__ bpref,
                            int* __restrict__ offsets) {
    __shared__ int sm[256];
    int t = threadIdx.x;
    int i = blockIdx.x * 256 + t;
    int x = (i < N_NODES) ? counts[i] : 0;
    sm[t] = x;
    __syncthreads();
    for (int off = 1; off < 256; off <<= 1) {
        int v = (t >= off) ? sm[t - off] : 0;
        __syncthreads();
        sm[t] += v;
        __syncthreads();
    }
    if (i <= N_NODES) offsets[i] = bpref[blockIdx.x] + sm[t] - x;
}

__global__ void scatter_kernel(const int* __restrict__ src, const int* __restrict__ dst,
                               const int* __restrict__ offsets, int* __restrict__ cursor,
                               int* __restrict__ srcs_sorted) {
    int e = blockIdx.x * blockDim.x + threadIdx.x;
    if (e >= N_EDGES) return;
    int d = dst[e];
    int pos = offsets[d] + atomicAdd(&cursor[d], 1);
    srcs_sorted[pos] = src[e];
}

// ---------------- weight conversion (merged) ----------------
// i < 128*128: W1[k][n] -> w1t[n][k]; next 48*128: W2 padded to 48 rows
__global__ void conv_w_kernel(const float* __restrict__ W1, const float* __restrict__ W2,
                              __bf16* __restrict__ w1t, __bf16* __restrict__ w2t) {
    int i = blockIdx.x * blockDim.x + threadIdx.x;
    if (i < 128 * 128) {
        int n = i >> 7, k = i & 127;
        w1t[i] = (__bf16)W1[k * 128 + n];
    } else if (i < 128 * 128 + 48 * 128) {
        int j = i - 128 * 128;
        int n = j >> 7, k = j & 127;
        w2t[j] = (n < CLS) ? (__bf16)W2[k * CLS + n] : (__bf16)0.0f;
    }
}

// ---------------- MFMA GEMMs ----------------
// features fp32 [N,128] @ w1t -> feat1b[N,128] bf16 (conversion fused).
__global__ __launch_bounds__(256) void gemm1_mfma(const float* __restrict__ A,
                                                  const __bf16* __restrict__ Wt,
                                                  __bf16* __restrict__ outb) {
    int wave = threadIdx.x >> 6, lane = threadIdx.x & 63;
    int m0 = blockIdx.x * 64 + wave * 16;
    int row = m0 + (lane & 15);
    int rowc = row < N_NODES ? row : N_NODES - 1;   // clamped read; writes guarded
    int ko = (lane >> 4) * 8;

    f32x4 acc[8];
    #pragma unroll
    for (int t = 0; t < 8; ++t)
        #pragma unroll
        for (int r = 0; r < 4; ++r) acc[t][r] = 0.f;

    for (int ks = 0; ks < 128; ks += 32) {
        const float* ap = A + (size_t)rowc * 128 + ks + ko;
        float4 u = *(const float4*)ap;
        float4 v = *(const float4*)(ap + 4);
        bf16x8 a;
        a[0] = (__bf16)u.x; a[1] = (__bf16)u.y; a[2] = (__bf16)u.z; a[3] = (__bf16)u.w;
        a[4] = (__bf16)v.x; a[5] = (__bf16)v.y; a[6] = (__bf16)v.z; a[7] = (__bf16)v.w;
        #pragma unroll
        for (int t = 0; t < 8; ++t) {
            bf16x8 b = *(const bf16x8*)(Wt + (size_t)(t * 16 + (lane & 15)) * 128 + ks + ko);
            acc[t] = __builtin_amdgcn_mfma_f32_16x16x32_bf16(a, b, acc[t], 0, 0, 0);
        }
    }
    int rbase = m0 + (lane >> 4) * 4;
    #pragma unroll
    for (int t = 0; t < 8; ++t) {
        int gcol = t * 16 + (lane & 15);
        #pragma unroll
        for (int r = 0; r < 4; ++r) {
            int grow = rbase + r;
            if (grow < N_NODES) outb[(size_t)grow * 128 + gcol] = (__bf16)acc[t][r];
        }
    }
}

// hbufb[N,128]bf16 @ w2t(48x128) -> feat2[N,40] fp32 (stride 40)
__global__ __launch_bounds__(256) void gemm2_mfma(const __bf16* __restrict__ A,
                                                  const __bf16* __restrict__ Wt,
                                                  float* __restrict__ out) {
    int wave = threadIdx.x >> 6, lane = threadIdx.x & 63;
    int m0 = blockIdx.x * 64 + wave * 16;
    int row = m0 + (lane & 15);
    int rowc = row < N_NODES ? row : N_NODES - 1;
    int ko = (lane >> 4) * 8;

    f32x4 acc[3];
    #pragma unroll
    for (int t = 0; t < 3; ++t)
        #pragma unroll
        for (int r = 0; r < 4; ++r) acc[t][r] = 0.f;

    for (int ks = 0; ks < 128; ks += 32) {
        bf16x8 a = *(const bf16x8*)(A + (size_t)rowc * 128 + ks + ko);
        #pragma unroll
        for (int t = 0; t < 3; ++t) {
            bf16x8 b = *(const bf16x8*)(Wt + (size_t)(t * 16 + (lane & 15)) * 128 + ks + ko);
            acc[t] = __builtin_amdgcn_mfma_f32_16x16x32_bf16(a, b, acc[t], 0, 0, 0);
        }
    }
    int rbase = m0 + (lane >> 4) * 4;
    #pragma unroll
    for (int t = 0; t < 3; ++t) {
        int gcol = t * 16 + (lane & 15);
        if (gcol >= CLS) continue;
        #pragma unroll
        for (int r = 0; r < 4; ++r) {
            int grow = rbase + r;
            if (grow < N_NODES) out[(size_t)grow * CLS + gcol] = acc[t][r];
        }
    }
}

// ---------------- attention dot products ----------------
__global__ void elr1_kernel(const __bf16* __restrict__ feat1b,
                            const float* __restrict__ al, const float* __restrict__ ar,
                            float* __restrict__ el, float* __restrict__ er) {
    int idx = blockIdx.x * blockDim.x + threadIdx.x;
    if (idx >= N_NODES * HEADS) return;
    int n = idx >> 3, h = idx & 7;
    const __bf16* f = feat1b + (size_t)n * F1 + h * HID;
    float a = 0.f, b = 0.f;
    #pragma unroll
    for (int d = 0; d < HID; ++d) {
        float v = (float)f[d];
        a += v * al[h * HID + d];
        b += v * ar[h * HID + d];
    }
    el[idx] = a;
    er[idx] = b;
}

__global__ void elr2_kernel(const float* __restrict__ feat2,
                            const float* __restrict__ al, const float* __restrict__ ar,
                            float* __restrict__ el, float* __restrict__ er) {
    int n = blockIdx.x * blockDim.x + threadIdx.x;
    if (n >= N_NODES) return;
    const float* f = feat2 + (size_t)n * CLS;
    float a = 0.f, b = 0.f;
    #pragma unroll
    for (int c = 0; c < CLS; ++c) {
        a += f[c] * al[c];
        b += f[c] * ar[c];
    }
    el[n] = a;
    er[n] = b;
}

// ---------------- softmax (alpha precompute) ----------------
// Layer 1: wave per node; lane = slot*8 + h. Writes alpha8[(off+e)*8+h] coalesced.
__global__ void softmax1_kernel(const int* __restrict__ offsets, const int* __restrict__ srcs,
                                const float* __restrict__ el, const float* __restrict__ er,
                                float* __restrict__ alpha8) {
    int wave = threadIdx.x >> 6;
    int lane = threadIdx.x & 63;
    int d = blockIdx.x * 4 + wave;
    if (d >= N_NODES) return;
    int off = offsets[d];
    int deg = offsets[d + 1] - off;
    if (deg == 0) return;

    int h = lane & 7, slot = lane >> 3;
    float er_d = er[d * 8 + h];

    float m = NEG_INF, l = 0.f;
    for (int base = 0; base < deg; base += 8) {
        int e = base + slot;
        float sc = NEG_INF;
        if (e < deg) {
            int s = srcs[off + e];
            sc = leaky(el[s * 8 + h] + er_d);
        }
        float mn = fmaxf(m, sc);
        float f1 = (m  == NEG_INF) ? 0.f : __expf(m - mn);
        float f2 = (sc == NEG_INF) ? 0.f : __expf(sc - mn);
        l = l * f1 + f2;
        m = mn;
    }
    #pragma unroll
    for (int mask = 8; mask <= 32; mask <<= 1) {
        float m2 = __shfl_xor(m, mask, 64);
        float l2 = __shfl_xor(l, mask, 64);
        float mn = fmaxf(m, m2);
        float f1 = (m  == NEG_INF) ? 0.f : __expf(m - mn);
        float f2 = (m2 == NEG_INF) ? 0.f : __expf(m2 - mn);
        l = l * f1 + l2 * f2;
        m = mn;
    }
    float inv_l = 1.f / (l + 1e-9f);

    for (int base = 0; base < deg; base += 8) {
        int e = base + slot;
        if (e < deg) {
            int s = srcs[off + e];
            float sc = leaky(el[s * 8 + h] + er_d);
            alpha8[(size_t)(off + e) * 8 + h] = __expf(sc - m) * inv_l;
        }
    }
}

// Layer 2: wave per node; lane = edge slot. Writes alpha2[off+e] coalesced.
__global__ void softmax2_kernel(const int* __restrict__ offsets, const int* __restrict__ srcs,
                                const float* __restrict__ el, const float* __restrict__ er,
                                float* __restrict__ alpha2) {
    int wave = threadIdx.x >> 6;
    int lane = threadIdx.x & 63;
    int d = blockIdx.x * 4 + wave;
    if (d >= N_NODES) return;
    int off = offsets[d];
    int deg = offsets[d + 1] - off;
    if (deg == 0) return;

    float er_d = er[d];

    float m = NEG_INF, l = 0.f;
    for (int base = 0; base < deg; base += 64) {
        int e = base + lane;
        float sc = NEG_INF;
        if (e < deg) {
            int s = srcs[off + e];
            sc = leaky(el[s] + er_d);
        }
        float mn = fmaxf(m, sc);
        float f1 = (m  == NEG_INF) ? 0.f : __expf(m - mn);
        float f2 = (sc == NEG_INF) ? 0.f : __expf(sc - mn);
        l = l * f1 + f2;
        m = mn;
    }
    #pragma unroll
    for (int mask = 1; mask <= 32; mask <<= 1) {
        float m2 = __shfl_xor(m, mask, 64);
        float l2 = __shfl_xor(l, mask, 64);
        float mn = fmaxf(m, m2);
        float f1 = (m  == NEG_INF) ? 0.f : __expf(m - mn);
        float f2 = (m2 == NEG_INF) ? 0.f : __expf(m2 - mn);
        l = l * f1 + l2 * f2;
        m = mn;
    }
    float inv_l = 1.f / (l + 1e-9f);

    for (int base = 0; base < deg; base += 64) {
        int e = base + lane;
        if (e < deg) {
            int s = srcs[off + e];
            float sc = leaky(el[s] + er_d);
            alpha2[off + e] = __expf(sc - m) * inv_l;
        }
    }
}

// ---------------- aggregation (pure CSR gather, 16 lanes/node) ----------------
// Layer 1: lane fg covers features fg*8..fg*8+7 (head fg>>1). 4-edge unroll.
__global__ __launch_bounds__(256) void agg1_kernel(const int* __restrict__ offsets,
                                                   const int* __restrict__ srcs,
                                                   const float* __restrict__ alpha8,
                                                   const __bf16* __restrict__ feat1b,
                                                   const float* __restrict__ b1,
                                                   __bf16* __restrict__ hbufb) {
    int d = blockIdx.x * 16 + (threadIdx.x >> 4);
    if (d >= N_NODES) return;
    int fg = threadIdx.x & 15;
    int hd = fg >> 1;
    int off = offsets[d];
    int deg = offsets[d + 1] - off;

    float acc[8];
    #pragma unroll
    for (int i = 0; i < 8; ++i) acc[i] = 0.f;

    int e = 0;
    for (; e + 4 <= deg; e += 4) {
        int s0 = srcs[off + e + 0];
        int s1 = srcs[off + e + 1];
        int s2 = srcs[off + e + 2];
        int s3 = srcs[off + e + 3];
        float a0 = alpha8[(size_t)(off + e + 0) * 8 + hd];
        float a1 = alpha8[(size_t)(off + e + 1) * 8 + hd];
        float a2 = alpha8[(size_t)(off + e + 2) * 8 + hd];
        float a3 = alpha8[(size_t)(off + e + 3) * 8 + hd];
        bf16x8 p0 = *(const bf16x8*)(feat1b + (size_t)s0 * F1 + fg * 8);
        bf16x8 p1 = *(const bf16x8*)(feat1b + (size_t)s1 * F1 + fg * 8);
        bf16x8 p2 = *(const bf16x8*)(feat1b + (size_t)s2 * F1 + fg * 8);
        bf16x8 p3 = *(const bf16x8*)(feat1b + (size_t)s3 * F1 + fg * 8);
        #pragma unroll
        for (int i = 0; i < 8; ++i) acc[i] += a0 * (float)p0[i];
        #pragma unroll
        for (int i = 0; i < 8; ++i) acc[i] += a1 * (float)p1[i];
        #pragma unroll
        for (int i = 0; i < 8; ++i) acc[i] += a2 * (float)p2[i];
        #pragma unroll
        for (int i = 0; i < 8; ++i) acc[i] += a3 * (float)p3[i];
    }
    for (; e < deg; ++e) {
        int s = srcs[off + e];
        float a = alpha8[(size_t)(off + e) * 8 + hd];
        bf16x8 p = *(const bf16x8*)(feat1b + (size_t)s * F1 + fg * 8);
        #pragma unroll
        for (int i = 0; i < 8; ++i) acc[i] += a * (float)p[i];
    }
    bf16x8 o;
    #pragma unroll
    for (int i = 0; i < 8; ++i) {
        float v = acc[i] + b1[fg * 8 + i];
        v = v > 0.f ? v : expm1f(v);
        o[i] = (__bf16)v;
    }
    *(bf16x8*)(hbufb + (size_t)d * F1 + fg * 8) = o;
}

// Layer 2: lane cg<10 covers classes cg*4..cg*4+3 (float4, stride 40).
__global__ __launch_bounds__(256) void agg2_kernel(const int* __restrict__ offsets,
                                                   const int* __restrict__ srcs,
                                                   const float* __restrict__ alpha2,
                                                   const float* __restrict__ feat2,
                                                   const float* __restrict__ b2,
                                                   float* __restrict__ out) {
    int d = blockIdx.x * 16 + (threadIdx.x >> 4);
    if (d >= N_NODES) return;
    int cg = threadIdx.x & 15;
    if (cg >= 10) return;
    int off = offsets[d];
    int deg = offsets[d + 1] - off;

    float acc[4];
    #pragma unroll
    for (int i = 0; i < 4; ++i) acc[i] = 0.f;

    int e = 0;
    for (; e + 4 <= deg; e += 4) {
        int s0 = srcs[off + e + 0];
        int s1 = srcs[off + e + 1];
        int s2 = srcs[off + e + 2];
        int s3 = srcs[off + e + 3];
        float a0 = alpha2[off + e + 0];
        float a1 = alpha2[off + e + 1];
        float a2 = alpha2[off + e + 2];
        float a3 = alpha2[off + e + 3];
        float4 p0 = *(const float4*)(feat2 + (size_t)s0 * CLS + cg * 4);
        float4 p1 = *(const float4*)(feat2 + (size_t)s1 * CLS + cg * 4);
        float4 p2 = *(const float4*)(feat2 + (size_t)s2 * CLS + cg * 4);
        float4 p3 = *(const float4*)(feat2 + (size_t)s3 * CLS + cg * 4);
        acc[0] += a0 * p0.x; acc[1] += a0 * p0.y; acc[2] += a0 * p0.z; acc[3] += a0 * p0.w;
        acc[0] += a1 * p1.x; acc[1] += a1 * p1.y; acc[2] += a1 * p1.z; acc[3] += a1 * p1.w;
        acc[0] += a2 * p2.x; acc[1] += a2 * p2.y; acc[2] += a2 * p2.z; acc[3] += a2 * p2.w;
        acc[0] += a3 * p3.x; acc[1] += a3 * p3.y; acc[2] += a3 * p3.z; acc[3] += a3 * p3.w;
    }
    for (; e < deg; ++e) {
        int s = srcs[off + e];
        float a = alpha2[off + e];
        float4 p = *(const float4*)(feat2 + (size_t)s * CLS + cg * 4);
        acc[0] += a * p.x; acc[1] += a * p.y; acc[2] += a * p.z; acc[3] += a * p.w;
    }
    float4 o;
    o.x = acc[0] + b2[cg * 4 + 0];
    o.y = acc[1] + b2[cg * 4 + 1];
    o.z = acc[2] + b2[cg * 4 + 2];
    o.w = acc[3] + b2[cg * 4 + 3];
    *(float4*)(out + (size_t)d * CLS + cg * 4) = o;
}

// ---------------- launch ----------------
extern "C" void kernel_launch(void* const* d_in, const int* in_sizes, int n_in,
                              void* d_out, int out_size, void* d_ws, size_t ws_size,
                              hipStream_t stream) {
    const float* features = (const float*)d_in[0];
    const int*   esrc     = (const int*)d_in[1];
    const int*   edst     = (const int*)d_in[2];
    const float* W1       = (const float*)d_in[3];
    const float* al1      = (const float*)d_in[4];
    const float* ar1      = (const float*)d_in[5];
    const float* b1       = (const float*)d_in[6];
    const float* W2       = (const float*)d_in[7];
    const float* al2      = (const float*)d_in[8];
    const float* ar2      = (const float*)d_in[9];
    const float* b2       = (const float*)d_in[10];
    float* out = (float*)d_out;

    float* ws = (float*)d_ws;
    float* feat2   = ws;                       // 2,000,000 fp32 (N x 40)
    float* el1     = ws + 2000000;             // 400,000
    float* er1     = ws + 2400000;             // 400,000
    float* el2     = ws + 2800000;             // 50,000
    float* er2     = ws + 2850000;             // 50,000
    int*   counts  = (int*)(ws + 2900000);     // 50,000
    int*   cursor  = (int*)(ws + 2950000);     // 50,000 (adjacent for joint zero)
    int*   offsets = (int*)(ws + 3000000);     // 50,001
    int*   bsum    = (int*)(ws + 3060000);     // 256
    int*   bpref   = (int*)(ws + 3061000);     // 256
    int*   srcs    = (int*)(ws + 3062000);     // 800,000
    float* alpha8  = ws + 3900000;             // 6,400,000 (E x 8)
    float* alpha2  = ws + 10300000;            // 800,000
    __bf16* feat1b = (__bf16*)(ws + 11100000); // 6,400,000 bf16 (3.2M slots)
    __bf16* hbufb  = (__bf16*)(ws + 14300000); // 6,400,000 bf16 (3.2M slots)
    __bf16* w1t    = (__bf16*)(ws + 17500000); // 16,384 bf16
    __bf16* w2t    = (__bf16*)(ws + 17510000); // 6,144 bf16
    // total ~17.52M floats = 70.1 MB

    const int B = 256;
    const int NB = (N_NODES + 255) / 256;

    // CSR build
    zero_int_kernel<<<(100000 + B - 1) / B, B, 0, stream>>>(counts, 100000);
    hist_kernel<<<(N_EDGES + B - 1) / B, B, 0, stream>>>(edst, counts);
    reduce_kernel<<<NB, 256, 0, stream>>>(counts, bsum);
    scanb_kernel<<<1, 256, 0, stream>>>(bsum, bpref, NB);
    scan_kernel<<<NB, 256, 0, stream>>>(counts, bpref, offsets);
    scatter_kernel<<<(N_EDGES + B - 1) / B, B, 0, stream>>>(esrc, edst, offsets, cursor, srcs);

    // weight conversion
    conv_w_kernel<<<(128 * 128 + 48 * 128 + B - 1) / B, B, 0, stream>>>(W1, W2, w1t, w2t);

    // layer 1
    gemm1_mfma<<<(N_NODES + 63) / 64, 256, 0, stream>>>(features, w1t, feat1b);
    elr1_kernel<<<(N_NODES * HEADS + B - 1) / B, B, 0, stream>>>(feat1b, al1, ar1, el1, er1);
    softmax1_kernel<<<(N_NODES + 3) / 4, B, 0, stream>>>(offsets, srcs, el1, er1, alpha8);
    agg1_kernel<<<(N_NODES + 15) / 16, B, 0, stream>>>(offsets, srcs, alpha8, feat1b, b1, hbufb);

    // layer 2
    gemm2_mfma<<<(N_NODES + 63) / 64, 256, 0, stream>>>(hbufb, w2t, feat2);
    elr2_kernel<<<(N_NODES + B - 1) / B, B, 0, stream>>>(feat2, al2, ar2, el2, er2);
    softmax2_kernel<<<(N_NODES + 3) / 4, B, 0, stream>>>(offsets, srcs, el2, er2, alpha2);
    agg2_kernel<<<(N_NODES + 15) / 16, B, 0, stream>>>(offsets, srcs, alpha2, feat2, b2, out);
}

// Round 7
// 305.690 us; speedup vs baseline: 1.0595x; 1.0595x over previous
//
#include <hip/hip_runtime.h>
#include <hip/hip_bf16.h>

#define N_NODES 50000
#define N_EDGES 800000
#define IN_F    128
#define HID     16
#define HEADS   8
#define F1      128   // HEADS*HID
#define CLS     40
#define CLSP    64    // padded bf16 feat2 stride
#define NEG     0.2f
#define NEG_INF (-__builtin_inff())
#define SWEEPS      8
#define SWEEP_RANGE 6250   // N_NODES / SWEEPS

typedef __bf16 bf16x8 __attribute__((ext_vector_type(8)));
typedef __bf16 bf16x4 __attribute__((ext_vector_type(4)));
typedef float  f32x4  __attribute__((ext_vector_type(4)));

__device__ __forceinline__ float leaky(float v) { return v >= 0.0f ? v : NEG * v; }

// ---------------- CSR build ----------------
__global__ void zero_int_kernel(int* __restrict__ p, int n) {
    int i = blockIdx.x * blockDim.x + threadIdx.x;
    if (i < n) p[i] = 0;
}

__global__ void hist_kernel(const int* __restrict__ dst, int* __restrict__ counts) {
    int e = blockIdx.x * blockDim.x + threadIdx.x;
    if (e < N_EDGES) atomicAdd(&counts[dst[e]], 1);
}

__global__ void reduce_kernel(const int* __restrict__ counts, int* __restrict__ bsum) {
    __shared__ int sm[256];
    int t = threadIdx.x;
    int i = blockIdx.x * 256 + t;
    sm[t] = (i < N_NODES) ? counts[i] : 0;
    __syncthreads();
    for (int off = 128; off > 0; off >>= 1) {
        if (t < off) sm[t] += sm[t + off];
        __syncthreads();
    }
    if (t == 0) bsum[blockIdx.x] = sm[0];
}

__global__ void scanb_kernel(const int* __restrict__ bsum, int* __restrict__ bpref, int nb) {
    __shared__ int sm[256];
    int t = threadIdx.x;
    int x = (t < nb) ? bsum[t] : 0;
    sm[t] = x;
    __syncthreads();
    for (int off = 1; off < 256; off <<= 1) {
        int v = (t >= off) ? sm[t - off] : 0;
        __syncthreads();
        sm[t] += v;
        __syncthreads();
    }
    bpref[t] = sm[t] - x;   // exclusive
}

__global__ void scan_kernel(const int* __restrict__ counts, const int* __restrict__ bpref,
                            int* __restrict__ offsets) {
    __shared__ int sm[256];
    int t = threadIdx.x;
    int i = blockIdx.x * 256 + t;
    int x = (i < N_NODES) ? counts[i] : 0;
    sm[t] = x;
    __syncthreads();
    for (int off = 1; off < 256; off <<= 1) {
        int v = (t >= off) ? sm[t - off] : 0;
        __syncthreads();
        sm[t] += v;
        __syncthreads();
    }
    if (i <= N_NODES) offsets[i] = bpref[blockIdx.x] + sm[t] - x;
}

// Swept scatter: sweep s only writes dst range [s*6250,(s+1)*6250) -> ~400KB
// L2-resident write window per sweep. Sweep-major block order keeps sweeps
// roughly time-sequential.
__global__ void scatter_kernel(const int* __restrict__ src, const int* __restrict__ dst,
                               const int* __restrict__ offsets, int* __restrict__ cursor,
                               int* __restrict__ srcs_sorted) {
    const int BPS = (N_EDGES + 255) / 256;   // blocks per sweep
    int sweep = blockIdx.x / BPS;
    int e = (blockIdx.x - sweep * BPS) * 256 + threadIdx.x;
    if (e >= N_EDGES) return;
    int d = dst[e];
    int lo = sweep * SWEEP_RANGE;
    if (d < lo || d >= lo + SWEEP_RANGE) return;
    int pos = offsets[d] + atomicAdd(&cursor[d], 1);
    srcs_sorted[pos] = src[e];
}

// ---------------- weight conversion (merged) ----------------
__global__ void conv_w_kernel(const float* __restrict__ W1, const float* __restrict__ W2,
                              __bf16* __restrict__ w1t, __bf16* __restrict__ w2t) {
    int i = blockIdx.x * blockDim.x + threadIdx.x;
    if (i < 128 * 128) {
        int n = i >> 7, k = i & 127;
        w1t[i] = (__bf16)W1[k * 128 + n];
    } else if (i < 128 * 128 + CLSP * 128) {
        int j = i - 128 * 128;
        int n = j >> 7, k = j & 127;
        w2t[j] = (n < CLS) ? (__bf16)W2[k * CLS + n] : (__bf16)0.0f;
    }
}

// ---------------- MFMA GEMMs ----------------
// features fp32 [N,128] @ w1t -> feat1b[N,128] bf16 (conversion fused).
__global__ __launch_bounds__(256) void gemm1_mfma(const float* __restrict__ A,
                                                  const __bf16* __restrict__ Wt,
                                                  __bf16* __restrict__ outb) {
    int wave = threadIdx.x >> 6, lane = threadIdx.x & 63;
    int m0 = blockIdx.x * 64 + wave * 16;
    int row = m0 + (lane & 15);
    int rowc = row < N_NODES ? row : N_NODES - 1;   // clamped read; writes guarded
    int ko = (lane >> 4) * 8;

    f32x4 acc[8];
    #pragma unroll
    for (int t = 0; t < 8; ++t)
        #pragma unroll
        for (int r = 0; r < 4; ++r) acc[t][r] = 0.f;

    for (int ks = 0; ks < 128; ks += 32) {
        const float* ap = A + (size_t)rowc * 128 + ks + ko;
        float4 u = *(const float4*)ap;
        float4 v = *(const float4*)(ap + 4);
        bf16x8 a;
        a[0] = (__bf16)u.x; a[1] = (__bf16)u.y; a[2] = (__bf16)u.z; a[3] = (__bf16)u.w;
        a[4] = (__bf16)v.x; a[5] = (__bf16)v.y; a[6] = (__bf16)v.z; a[7] = (__bf16)v.w;
        #pragma unroll
        for (int t = 0; t < 8; ++t) {
            bf16x8 b = *(const bf16x8*)(Wt + (size_t)(t * 16 + (lane & 15)) * 128 + ks + ko);
            acc[t] = __builtin_amdgcn_mfma_f32_16x16x32_bf16(a, b, acc[t], 0, 0, 0);
        }
    }
    int rbase = m0 + (lane >> 4) * 4;
    #pragma unroll
    for (int t = 0; t < 8; ++t) {
        int gcol = t * 16 + (lane & 15);
        #pragma unroll
        for (int r = 0; r < 4; ++r) {
            int grow = rbase + r;
            if (grow < N_NODES) outb[(size_t)grow * 128 + gcol] = (__bf16)acc[t][r];
        }
    }
}

// hbufb[N,128]bf16 @ w2t(64x128) -> feat2p[N,64] bf16 (cols 40..63 zero)
__global__ __launch_bounds__(256) void gemm2_mfma(const __bf16* __restrict__ A,
                                                  const __bf16* __restrict__ Wt,
                                                  __bf16* __restrict__ out) {
    int wave = threadIdx.x >> 6, lane = threadIdx.x & 63;
    int m0 = blockIdx.x * 64 + wave * 16;
    int row = m0 + (lane & 15);
    int rowc = row < N_NODES ? row : N_NODES - 1;
    int ko = (lane >> 4) * 8;

    f32x4 acc[4];
    #pragma unroll
    for (int t = 0; t < 4; ++t)
        #pragma unroll
        for (int r = 0; r < 4; ++r) acc[t][r] = 0.f;

    for (int ks = 0; ks < 128; ks += 32) {
        bf16x8 a = *(const bf16x8*)(A + (size_t)rowc * 128 + ks + ko);
        #pragma unroll
        for (int t = 0; t < 4; ++t) {
            bf16x8 b = *(const bf16x8*)(Wt + (size_t)(t * 16 + (lane & 15)) * 128 + ks + ko);
            acc[t] = __builtin_amdgcn_mfma_f32_16x16x32_bf16(a, b, acc[t], 0, 0, 0);
        }
    }
    int rbase = m0 + (lane >> 4) * 4;
    #pragma unroll
    for (int t = 0; t < 4; ++t) {
        int gcol = t * 16 + (lane & 15);
        #pragma unroll
        for (int r = 0; r < 4; ++r) {
            int grow = rbase + r;
            if (grow < N_NODES) out[(size_t)grow * CLSP + gcol] = (__bf16)acc[t][r];
        }
    }
}

// ---------------- attention dot products ----------------
__global__ void elr1_kernel(const __bf16* __restrict__ feat1b,
                            const float* __restrict__ al, const float* __restrict__ ar,
                            float* __restrict__ el, float* __restrict__ er) {
    int idx = blockIdx.x * blockDim.x + threadIdx.x;
    if (idx >= N_NODES * HEADS) return;
    int n = idx >> 3, h = idx & 7;
    const __bf16* f = feat1b + (size_t)n * F1 + h * HID;
    float a = 0.f, b = 0.f;
    #pragma unroll
    for (int d = 0; d < HID; ++d) {
        float v = (float)f[d];
        a += v * al[h * HID + d];
        b += v * ar[h * HID + d];
    }
    el[idx] = a;
    er[idx] = b;
}

__global__ void elr2_kernel(const __bf16* __restrict__ feat2p,
                            const float* __restrict__ al, const float* __restrict__ ar,
                            float* __restrict__ el, float* __restrict__ er) {
    int n = blockIdx.x * blockDim.x + threadIdx.x;
    if (n >= N_NODES) return;
    const __bf16* f = feat2p + (size_t)n * CLSP;
    float a = 0.f, b = 0.f;
    #pragma unroll
    for (int c = 0; c < CLS; ++c) {
        float v = (float)f[c];
        a += v * al[c];
        b += v * ar[c];
    }
    el[n] = a;
    er[n] = b;
}

// ---------------- fused GAT layer 1 ----------------
// Wave per node. Score phase: lane = slot*8 + h, scores held in sc[8] regs
// (deg<=64 fast path). Aggregate: q=lane>>4 (4-edge subgroups), fg=lane&15
// covers features fg*8..fg*8+7 (head fg>>1), 16B bf16x8 gathers.
__global__ void gat1_fused(const int* __restrict__ offsets, const int* __restrict__ srcs,
                           const float* __restrict__ el, const float* __restrict__ er,
                           const __bf16* __restrict__ feat1b, const float* __restrict__ b1,
                           __bf16* __restrict__ hbufb) {
    int wave = threadIdx.x >> 6;
    int lane = threadIdx.x & 63;
    int d = blockIdx.x * 4 + wave;
    if (d >= N_NODES) return;
    int off = offsets[d];
    int deg = offsets[d + 1] - off;

    int h = lane & 7, slot = lane >> 3;
    float er_d = er[d * 8 + h];
    int q  = lane >> 4;
    int fg = lane & 15;
    int hd = fg >> 1;
    float acc[8];
    #pragma unroll
    for (int i = 0; i < 8; ++i) acc[i] = 0.f;

    if (deg <= 64) {
        // ---- fast path: scores in registers ----
        float sc[8];
        float m = NEG_INF;
        #pragma unroll
        for (int it = 0; it < 8; ++it) {
            int e = it * 8 + slot;
            float v = NEG_INF;
            if (e < deg) {
                int s = srcs[off + e];
                v = leaky(el[s * 8 + h] + er_d);
            }
            sc[it] = v;
            m = fmaxf(m, v);
        }
        float l = 0.f;
        #pragma unroll
        for (int it = 0; it < 8; ++it)
            l += (sc[it] == NEG_INF) ? 0.f : __expf(sc[it] - m);
        #pragma unroll
        for (int mask = 8; mask <= 32; mask <<= 1) {
            float m2 = __shfl_xor(m, mask, 64);
            float l2 = __shfl_xor(l, mask, 64);
            float mn = fmaxf(m, m2);
            float f1 = (m  == NEG_INF) ? 0.f : __expf(m - mn);
            float f2 = (m2 == NEG_INF) ? 0.f : __expf(m2 - mn);
            l = l * f1 + l2 * f2;
            m = mn;
        }
        float inv_l = 1.f / (l + 1e-9f);

        #pragma unroll
        for (int it = 0; it < 8; ++it) {
            if (it * 8 < deg) {
                int e = it * 8 + slot;
                float alpha = 0.f;
                int s = 0;
                if (e < deg) {
                    s = srcs[off + e];
                    alpha = __expf(sc[it] - m) * inv_l;
                }
                #pragma unroll
                for (int sub = 0; sub < 2; ++sub) {
                    int k = sub * 4 + q;
                    float a  = __shfl(alpha, k * 8 + hd, 64);
                    int   se = __shfl(s,     k * 8,      64);
                    bf16x8 p = *(const bf16x8*)(feat1b + (size_t)se * F1 + fg * 8);
                    #pragma unroll
                    for (int i = 0; i < 8; ++i) acc[i] += a * (float)p[i];
                }
            }
        }
    } else {
        // ---- slow path: recompute scores (deg > 64, essentially never) ----
        float m = NEG_INF, l = 0.f;
        for (int base = 0; base < deg; base += 8) {
            int e = base + slot;
            float v = NEG_INF;
            if (e < deg) {
                int s = srcs[off + e];
                v = leaky(el[s * 8 + h] + er_d);
            }
            float mn = fmaxf(m, v);
            float f1 = (m == NEG_INF) ? 0.f : __expf(m - mn);
            float f2 = (v == NEG_INF) ? 0.f : __expf(v - mn);
            l = l * f1 + f2;
            m = mn;
        }
        #pragma unroll
        for (int mask = 8; mask <= 32; mask <<= 1) {
            float m2 = __shfl_xor(m, mask, 64);
            float l2 = __shfl_xor(l, mask, 64);
            float mn = fmaxf(m, m2);
            float f1 = (m  == NEG_INF) ? 0.f : __expf(m - mn);
            float f2 = (m2 == NEG_INF) ? 0.f : __expf(m2 - mn);
            l = l * f1 + l2 * f2;
            m = mn;
        }
        float inv_l = 1.f / (l + 1e-9f);

        for (int base = 0; base < deg; base += 8) {
            int e = base + slot;
            float alpha = 0.f;
            int s = 0;
            if (e < deg) {
                s = srcs[off + e];
                float v = leaky(el[s * 8 + h] + er_d);
                alpha = __expf(v - m) * inv_l;
            }
            #pragma unroll
            for (int sub = 0; sub < 2; ++sub) {
                int k = sub * 4 + q;
                float a  = __shfl(alpha, k * 8 + hd, 64);
                int   se = __shfl(s,     k * 8,      64);
                bf16x8 p = *(const bf16x8*)(feat1b + (size_t)se * F1 + fg * 8);
                #pragma unroll
                for (int i = 0; i < 8; ++i) acc[i] += a * (float)p[i];
            }
        }
    }

    #pragma unroll
    for (int i = 0; i < 8; ++i) {
        acc[i] += __shfl_xor(acc[i], 16, 64);
        acc[i] += __shfl_xor(acc[i], 32, 64);
    }
    if (q == 0) {
        bf16x8 o;
        #pragma unroll
        for (int i = 0; i < 8; ++i) {
            float v = acc[i] + b1[fg * 8 + i];
            v = v > 0.f ? v : expm1f(v);
            o[i] = (__bf16)v;
        }
        *(bf16x8*)(hbufb + (size_t)d * F1 + fg * 8) = o;
    }
}

// ---------------- fused GAT layer 2 ----------------
// Wave per node. Score: lane = edge slot (1 reg). Aggregate: q=lane>>4,
// cg=lane&15 covers classes cg*4..cg*4+3 of bf16 feat2p (stride 64).
__global__ void gat2_fused(const int* __restrict__ offsets, const int* __restrict__ srcs,
                           const float* __restrict__ el, const float* __restrict__ er,
                           const __bf16* __restrict__ feat2p, const float* __restrict__ b2,
                           float* __restrict__ out) {
    int wave = threadIdx.x >> 6;
    int lane = threadIdx.x & 63;
    int d = blockIdx.x * 4 + wave;
    if (d >= N_NODES) return;
    int off = offsets[d];
    int deg = offsets[d + 1] - off;

    float er_d = er[d];
    int q  = lane >> 4;
    int cg = lane & 15;
    float acc[4];
    #pragma unroll
    for (int i = 0; i < 4; ++i) acc[i] = 0.f;

    if (deg <= 64) {
        float sc = NEG_INF;
        int s0 = 0;
        if (lane < deg) {
            s0 = srcs[off + lane];
            sc = leaky(el[s0] + er_d);
        }
        float m = sc, l = (sc == NEG_INF) ? 0.f : 1.f;
        #pragma unroll
        for (int mask = 1; mask <= 32; mask <<= 1) {
            float m2 = __shfl_xor(m, mask, 64);
            float l2 = __shfl_xor(l, mask, 64);
            float mn = fmaxf(m, m2);
            float f1 = (m  == NEG_INF) ? 0.f : __expf(m - mn);
            float f2 = (m2 == NEG_INF) ? 0.f : __expf(m2 - mn);
            l = l * f1 + l2 * f2;
            m = mn;
        }
        float inv_l = 1.f / (l + 1e-9f);
        float alpha = (lane < deg) ? __expf(sc - m) * inv_l : 0.f;

        int nsub = (min(deg, 64) + 3) >> 2;
        for (int sub = 0; sub < nsub; ++sub) {
            int k = sub * 4 + q;
            float a  = __shfl(alpha, k, 64);
            int   se = __shfl(s0,    k, 64);
            bf16x4 p = *(const bf16x4*)(feat2p + (size_t)se * CLSP + cg * 4);
            acc[0] += a * (float)p[0];
            acc[1] += a * (float)p[1];
            acc[2] += a * (float)p[2];
            acc[3] += a * (float)p[3];
        }
    } else {
        float m = NEG_INF, l = 0.f;
        for (int base = 0; base < deg; base += 64) {
            int e = base + lane;
            float sc = NEG_INF;
            if (e < deg) {
                int s = srcs[off + e];
                sc = leaky(el[s] + er_d);
            }
            float mn = fmaxf(m, sc);
            float f1 = (m  == NEG_INF) ? 0.f : __expf(m - mn);
            float f2 = (sc == NEG_INF) ? 0.f : __expf(sc - mn);
            l = l * f1 + f2;
            m = mn;
        }
        #pragma unroll
        for (int mask = 1; mask <= 32; mask <<= 1) {
            float m2 = __shfl_xor(m, mask, 64);
            float l2 = __shfl_xor(l, mask, 64);
            float mn = fmaxf(m, m2);
            float f1 = (m  == NEG_INF) ? 0.f : __expf(m - mn);
            float f2 = (m2 == NEG_INF) ? 0.f : __expf(m2 - mn);
            l = l * f1 + l2 * f2;
            m = mn;
        }
        float inv_l = 1.f / (l + 1e-9f);

        for (int base = 0; base < deg; base += 64) {
            int e = base + lane;
            float alpha = 0.f;
            int s = 0;
            if (e < deg) {
                s = srcs[off + e];
                float sc = leaky(el[s] + er_d);
                alpha = __expf(sc - m) * inv_l;
            }
            int kmax = min(64, deg - base);
            int nsub = (kmax + 3) >> 2;
            for (int sub = 0; sub < nsub; ++sub) {
                int k = sub * 4 + q;
                float a  = __shfl(alpha, k, 64);
                int   se = __shfl(s,     k, 64);
                bf16x4 p = *(const bf16x4*)(feat2p + (size_t)se * CLSP + cg * 4);
                acc[0] += a * (float)p[0];
                acc[1] += a * (float)p[1];
                acc[2] += a * (float)p[2];
                acc[3] += a * (float)p[3];
            }
        }
    }

    #pragma unroll
    for (int i = 0; i < 4; ++i) {
        acc[i] += __shfl_xor(acc[i], 16, 64);
        acc[i] += __shfl_xor(acc[i], 32, 64);
    }
    if (lane < 10) {   // q==0, cg<10
        float4 o;
        o.x = acc[0] + b2[cg * 4 + 0];
        o.y = acc[1] + b2[cg * 4 + 1];
        o.z = acc[2] + b2[cg * 4 + 2];
        o.w = acc[3] + b2[cg * 4 + 3];
        *(float4*)(out + (size_t)d * CLS + cg * 4) = o;
    }
}

// ---------------- launch ----------------
extern "C" void kernel_launch(void* const* d_in, const int* in_sizes, int n_in,
                              void* d_out, int out_size, void* d_ws, size_t ws_size,
                              hipStream_t stream) {
    const float* features = (const float*)d_in[0];
    const int*   esrc     = (const int*)d_in[1];
    const int*   edst     = (const int*)d_in[2];
    const float* W1       = (const float*)d_in[3];
    const float* al1      = (const float*)d_in[4];
    const float* ar1      = (const float*)d_in[5];
    const float* b1       = (const float*)d_in[6];
    const float* W2       = (const float*)d_in[7];
    const float* al2      = (const float*)d_in[8];
    const float* ar2      = (const float*)d_in[9];
    const float* b2       = (const float*)d_in[10];
    float* out = (float*)d_out;

    float* ws = (float*)d_ws;
    float* el1     = ws;                       // 400,000
    float* er1     = ws + 400000;              // 400,000
    float* el2     = ws + 800000;              // 50,000
    float* er2     = ws + 850000;              // 50,000
    int*   counts  = (int*)(ws + 900000);      // 50,000
    int*   cursor  = (int*)(ws + 950000);      // 50,000 (adjacent for joint zero)
    int*   offsets = (int*)(ws + 1000000);     // 50,001
    int*   bsum    = (int*)(ws + 1060000);     // 256
    int*   bpref   = (int*)(ws + 1061000);     // 256
    int*   srcs    = (int*)(ws + 1062000);     // 800,000
    __bf16* feat1b = (__bf16*)(ws + 1900000);  // 6,400,000 bf16 (3.2M floats)
    __bf16* hbufb  = (__bf16*)(ws + 5100000);  // 6,400,000 bf16 (3.2M floats)
    __bf16* feat2p = (__bf16*)(ws + 8300000);  // 3,200,000 bf16 (1.6M floats)
    __bf16* w1t    = (__bf16*)(ws + 9900000);  // 16,384 bf16
    __bf16* w2t    = (__bf16*)(ws + 9910000);  // 8,192 bf16
    // total ~9.92M floats = 39.7 MB

    const int B = 256;
    const int NB = (N_NODES + 255) / 256;
    const int BPS = (N_EDGES + 255) / 256;

    // CSR build
    zero_int_kernel<<<(100000 + B - 1) / B, B, 0, stream>>>(counts, 100000);
    hist_kernel<<<BPS, B, 0, stream>>>(edst, counts);
    reduce_kernel<<<NB, 256, 0, stream>>>(counts, bsum);
    scanb_kernel<<<1, 256, 0, stream>>>(bsum, bpref, NB);
    scan_kernel<<<NB, 256, 0, stream>>>(counts, bpref, offsets);
    scatter_kernel<<<SWEEPS * BPS, B, 0, stream>>>(esrc, edst, offsets, cursor, srcs);

    // weight conversion
    conv_w_kernel<<<(128 * 128 + CLSP * 128 + B - 1) / B, B, 0, stream>>>(W1, W2, w1t, w2t);

    // layer 1
    gemm1_mfma<<<(N_NODES + 63) / 64, 256, 0, stream>>>(features, w1t, feat1b);
    elr1_kernel<<<(N_NODES * HEADS + B - 1) / B, B, 0, stream>>>(feat1b, al1, ar1, el1, er1);
    gat1_fused<<<(N_NODES + 3) / 4, B, 0, stream>>>(offsets, srcs, el1, er1, feat1b, b1, hbufb);

    // layer 2
    gemm2_mfma<<<(N_NODES + 63) / 64, 256, 0, stream>>>(hbufb, w2t, feat2p);
    elr2_kernel<<<(N_NODES + B - 1) / B, B, 0, stream>>>(feat2p, al2, ar2, el2, er2);
    gat2_fused<<<(N_NODES + 3) / 4, B, 0, stream>>>(offsets, srcs, el2, er2, feat2p, b2, out);
}

// Round 8
// 273.012 us; speedup vs baseline: 1.1864x; 1.1197x over previous
//
#include <hip/hip_runtime.h>
#include <hip/hip_bf16.h>

#define N_NODES 50000
#define N_EDGES 800000
#define IN_F    128
#define HID     16
#define HEADS   8
#define F1      128   // HEADS*HID
#define CLS     40
#define CLSP    64    // padded bf16 feat2 stride
#define NEG     0.2f
#define NEG_INF (-__builtin_inff())
#define SWEEPS      8
#define SWEEP_RANGE 6250   // N_NODES / SWEEPS
#define STRIDE      96     // padded CSR slot count per node (P(deg>96) ~ 0)

typedef __bf16 bf16x8 __attribute__((ext_vector_type(8)));
typedef float  f32x4  __attribute__((ext_vector_type(4)));
typedef float  f32x2  __attribute__((ext_vector_type(2)));

__device__ __forceinline__ float leaky(float v) { return v >= 0.0f ? v : NEG * v; }
__device__ __forceinline__ f32x2 unpk(unsigned u) {
    f32x2 r;
    r.x = __uint_as_float(u << 16);
    r.y = __uint_as_float(u & 0xffff0000u);
    return r;
}

// ---------------- setup: zero cursor + weight transposes ----------------
__global__ void setup_kernel(const float* __restrict__ W1, const float* __restrict__ W2,
                             __bf16* __restrict__ w1t, __bf16* __restrict__ w2t,
                             int* __restrict__ cursor) {
    int i = blockIdx.x * blockDim.x + threadIdx.x;
    if (i < N_NODES) cursor[i] = 0;
    if (i < 128 * 128) {
        int n = i >> 7, k = i & 127;
        w1t[i] = (__bf16)W1[k * 128 + n];
    }
    if (i < CLSP * 128) {
        int n = i >> 7, k = i & 127;
        w2t[i] = (n < CLS) ? (__bf16)W2[k * CLS + n] : (__bf16)0.0f;
    }
}

// ---------------- swept scatter into padded CSR ----------------
// Sweep s handles dst in [s*6250,(s+1)*6250): writes land in a 2.4MB window.
__global__ void scatter_kernel(const int* __restrict__ src, const int* __restrict__ dst,
                               int* __restrict__ cursor, int* __restrict__ srcs_sorted) {
    const int BPS = (N_EDGES + 255) / 256;
    int sweep = blockIdx.x / BPS;
    int e = (blockIdx.x - sweep * BPS) * 256 + threadIdx.x;
    if (e >= N_EDGES) return;
    int d = dst[e];
    int lo = sweep * SWEEP_RANGE;
    if (d < lo || d >= lo + SWEEP_RANGE) return;
    int pos = d * STRIDE + atomicAdd(&cursor[d], 1);
    srcs_sorted[pos] = src[e];
}

// ---------------- GEMM1 + fused elr1 epilogue ----------------
// features fp32 [N,128] @ w1t -> feat1b[N,128] bf16; col tile t == head t.
__global__ __launch_bounds__(256) void gemm1_mfma(const float* __restrict__ A,
                                                  const __bf16* __restrict__ Wt,
                                                  const float* __restrict__ al1,
                                                  const float* __restrict__ ar1,
                                                  __bf16* __restrict__ outb,
                                                  float* __restrict__ el,
                                                  float* __restrict__ er) {
    int wave = threadIdx.x >> 6, lane = threadIdx.x & 63;
    int m0 = blockIdx.x * 64 + wave * 16;
    int c = lane & 15;
    int row = m0 + c;
    int rowc = row < N_NODES ? row : N_NODES - 1;   // clamped read; writes guarded
    int ko = (lane >> 4) * 8;

    f32x4 acc[8];
    #pragma unroll
    for (int t = 0; t < 8; ++t)
        #pragma unroll
        for (int r = 0; r < 4; ++r) acc[t][r] = 0.f;

    for (int ks = 0; ks < 128; ks += 32) {
        const float* ap = A + (size_t)rowc * 128 + ks + ko;
        float4 u = *(const float4*)ap;
        float4 v = *(const float4*)(ap + 4);
        bf16x8 a;
        a[0] = (__bf16)u.x; a[1] = (__bf16)u.y; a[2] = (__bf16)u.z; a[3] = (__bf16)u.w;
        a[4] = (__bf16)v.x; a[5] = (__bf16)v.y; a[6] = (__bf16)v.z; a[7] = (__bf16)v.w;
        #pragma unroll
        for (int t = 0; t < 8; ++t) {
            bf16x8 b = *(const bf16x8*)(Wt + (size_t)(t * 16 + c) * 128 + ks + ko);
            acc[t] = __builtin_amdgcn_mfma_f32_16x16x32_bf16(a, b, acc[t], 0, 0, 0);
        }
    }
    int rbase = m0 + (lane >> 4) * 4;
    #pragma unroll
    for (int t = 0; t < 8; ++t) {
        int gcol = t * 16 + c;
        #pragma unroll
        for (int r = 0; r < 4; ++r) {
            int grow = rbase + r;
            if (grow < N_NODES) outb[(size_t)grow * 128 + gcol] = (__bf16)acc[t][r];
        }
    }
    // fused elr1: el[row][t] = sum_c acc(row, t*16+c)*al1[t*16+c]
    #pragma unroll
    for (int t = 0; t < 8; ++t) {
        float alv = al1[t * 16 + c];
        float arv = ar1[t * 16 + c];
        float pe[4], pr[4];
        #pragma unroll
        for (int r = 0; r < 4; ++r) { pe[r] = acc[t][r] * alv; pr[r] = acc[t][r] * arv; }
        #pragma unroll
        for (int mask = 1; mask <= 8; mask <<= 1) {
            #pragma unroll
            for (int r = 0; r < 4; ++r) {
                pe[r] += __shfl_xor(pe[r], mask, 64);
                pr[r] += __shfl_xor(pr[r], mask, 64);
            }
        }
        if (c == 0) {
            #pragma unroll
            for (int r = 0; r < 4; ++r) {
                int grow = rbase + r;
                if (grow < N_NODES) {
                    el[grow * 8 + t] = pe[r];
                    er[grow * 8 + t] = pr[r];
                }
            }
        }
    }
}

// ---------------- GEMM2 + fused elr2 epilogue ----------------
// hbufb[N,128]bf16 @ w2t(64x128) -> feat2p[N,64] bf16 (cols 40..63 zero)
__global__ __launch_bounds__(256) void gemm2_mfma(const __bf16* __restrict__ A,
                                                  const __bf16* __restrict__ Wt,
                                                  const float* __restrict__ al2,
                                                  const float* __restrict__ ar2,
                                                  __bf16* __restrict__ out,
                                                  float* __restrict__ el,
                                                  float* __restrict__ er) {
    int wave = threadIdx.x >> 6, lane = threadIdx.x & 63;
    int m0 = blockIdx.x * 64 + wave * 16;
    int c = lane & 15;
    int row = m0 + c;
    int rowc = row < N_NODES ? row : N_NODES - 1;
    int ko = (lane >> 4) * 8;

    f32x4 acc[4];
    #pragma unroll
    for (int t = 0; t < 4; ++t)
        #pragma unroll
        for (int r = 0; r < 4; ++r) acc[t][r] = 0.f;

    for (int ks = 0; ks < 128; ks += 32) {
        bf16x8 a = *(const bf16x8*)(A + (size_t)rowc * 128 + ks + ko);
        #pragma unroll
        for (int t = 0; t < 4; ++t) {
            bf16x8 b = *(const bf16x8*)(Wt + (size_t)(t * 16 + c) * 128 + ks + ko);
            acc[t] = __builtin_amdgcn_mfma_f32_16x16x32_bf16(a, b, acc[t], 0, 0, 0);
        }
    }
    int rbase = m0 + (lane >> 4) * 4;
    #pragma unroll
    for (int t = 0; t < 4; ++t) {
        int gcol = t * 16 + c;
        #pragma unroll
        for (int r = 0; r < 4; ++r) {
            int grow = rbase + r;
            if (grow < N_NODES) out[(size_t)grow * CLSP + gcol] = (__bf16)acc[t][r];
        }
    }
    // fused elr2: el[row] = sum_{col<40} acc*al2[col]
    float pe[4] = {0.f, 0.f, 0.f, 0.f}, pr[4] = {0.f, 0.f, 0.f, 0.f};
    #pragma unroll
    for (int t = 0; t < 3; ++t) {
        int idx = t * 16 + c;
        float alv = (idx < CLS) ? al2[idx] : 0.f;
        float arv = (idx < CLS) ? ar2[idx] : 0.f;
        #pragma unroll
        for (int r = 0; r < 4; ++r) { pe[r] += acc[t][r] * alv; pr[r] += acc[t][r] * arv; }
    }
    #pragma unroll
    for (int mask = 1; mask <= 8; mask <<= 1) {
        #pragma unroll
        for (int r = 0; r < 4; ++r) {
            pe[r] += __shfl_xor(pe[r], mask, 64);
            pr[r] += __shfl_xor(pr[r], mask, 64);
        }
    }
    if (c == 0) {
        #pragma unroll
        for (int r = 0; r < 4; ++r) {
            int grow = rbase + r;
            if (grow < N_NODES) { el[grow] = pe[r]; er[grow] = pr[r]; }
        }
    }
}

// ---------------- fused GAT layer 1 ----------------
__global__ void gat1_fused(const int* __restrict__ degs, const int* __restrict__ srcs,
                           const float* __restrict__ el, const float* __restrict__ er,
                           const __bf16* __restrict__ feat1b, const float* __restrict__ b1,
                           __bf16* __restrict__ hbufb) {
    int wave = threadIdx.x >> 6;
    int lane = threadIdx.x & 63;
    int d = blockIdx.x * 4 + wave;
    if (d >= N_NODES) return;
    int off = d * STRIDE;
    int deg = degs[d];

    int h = lane & 7, slot = lane >> 3;
    float er_d = er[d * 8 + h];
    int q  = lane >> 4;
    int fg = lane & 15;
    int hd = fg >> 1;
    f32x2 accv[4];
    #pragma unroll
    for (int j = 0; j < 4; ++j) { accv[j].x = 0.f; accv[j].y = 0.f; }

    if (deg <= 64) {
        // ---- fast path: scores in registers ----
        float sc[8];
        float m = NEG_INF;
        #pragma unroll
        for (int it = 0; it < 8; ++it) {
            int e = it * 8 + slot;
            float v = NEG_INF;
            if (e < deg) {
                int s = srcs[off + e];
                v = leaky(el[s * 8 + h] + er_d);
            }
            sc[it] = v;
            m = fmaxf(m, v);
        }
        float l = 0.f;
        #pragma unroll
        for (int it = 0; it < 8; ++it)
            l += (sc[it] == NEG_INF) ? 0.f : __expf(sc[it] - m);
        #pragma unroll
        for (int mask = 8; mask <= 32; mask <<= 1) {
            float m2 = __shfl_xor(m, mask, 64);
            float l2 = __shfl_xor(l, mask, 64);
            float mn = fmaxf(m, m2);
            float f1 = (m  == NEG_INF) ? 0.f : __expf(m - mn);
            float f2 = (m2 == NEG_INF) ? 0.f : __expf(m2 - mn);
            l = l * f1 + l2 * f2;
            m = mn;
        }
        float inv_l = 1.f / (l + 1e-9f);

        #pragma unroll
        for (int it = 0; it < 8; ++it) {
            if (it * 8 < deg) {
                int e = it * 8 + slot;
                float alpha = 0.f;
                int s = 0;
                if (e < deg) {
                    s = srcs[off + e];
                    alpha = __expf(sc[it] - m) * inv_l;
                }
                #pragma unroll
                for (int sub = 0; sub < 2; ++sub) {
                    int k = sub * 4 + q;
                    float a  = __shfl(alpha, k * 8 + hd, 64);
                    int   se = __shfl(s,     k * 8,      64);
                    uint4 p = *(const uint4*)(feat1b + (size_t)se * F1 + fg * 8);
                    f32x2 av; av.x = a; av.y = a;
                    accv[0] += av * unpk(p.x);
                    accv[1] += av * unpk(p.y);
                    accv[2] += av * unpk(p.z);
                    accv[3] += av * unpk(p.w);
                }
            }
        }
    } else {
        // ---- slow path (deg > 64, essentially never) ----
        float m = NEG_INF, l = 0.f;
        for (int base = 0; base < deg; base += 8) {
            int e = base + slot;
            float v = NEG_INF;
            if (e < deg) {
                int s = srcs[off + e];
                v = leaky(el[s * 8 + h] + er_d);
            }
            float mn = fmaxf(m, v);
            float f1 = (m == NEG_INF) ? 0.f : __expf(m - mn);
            float f2 = (v == NEG_INF) ? 0.f : __expf(v - mn);
            l = l * f1 + f2;
            m = mn;
        }
        #pragma unroll
        for (int mask = 8; mask <= 32; mask <<= 1) {
            float m2 = __shfl_xor(m, mask, 64);
            float l2 = __shfl_xor(l, mask, 64);
            float mn = fmaxf(m, m2);
            float f1 = (m  == NEG_INF) ? 0.f : __expf(m - mn);
            float f2 = (m2 == NEG_INF) ? 0.f : __expf(m2 - mn);
            l = l * f1 + l2 * f2;
            m = mn;
        }
        float inv_l = 1.f / (l + 1e-9f);

        for (int base = 0; base < deg; base += 8) {
            int e = base + slot;
            float alpha = 0.f;
            int s = 0;
            if (e < deg) {
                s = srcs[off + e];
                float v = leaky(el[s * 8 + h] + er_d);
                alpha = __expf(v - m) * inv_l;
            }
            #pragma unroll
            for (int sub = 0; sub < 2; ++sub) {
                int k = sub * 4 + q;
                float a  = __shfl(alpha, k * 8 + hd, 64);
                int   se = __shfl(s,     k * 8,      64);
                uint4 p = *(const uint4*)(feat1b + (size_t)se * F1 + fg * 8);
                f32x2 av; av.x = a; av.y = a;
                accv[0] += av * unpk(p.x);
                accv[1] += av * unpk(p.y);
                accv[2] += av * unpk(p.z);
                accv[3] += av * unpk(p.w);
            }
        }
    }

    float acc[8];
    #pragma unroll
    for (int j = 0; j < 4; ++j) { acc[2 * j] = accv[j].x; acc[2 * j + 1] = accv[j].y; }
    #pragma unroll
    for (int i = 0; i < 8; ++i) {
        acc[i] += __shfl_xor(acc[i], 16, 64);
        acc[i] += __shfl_xor(acc[i], 32, 64);
    }
    if (q == 0) {
        bf16x8 o;
        #pragma unroll
        for (int i = 0; i < 8; ++i) {
            float v = acc[i] + b1[fg * 8 + i];
            v = v > 0.f ? v : expm1f(v);
            o[i] = (__bf16)v;
        }
        *(bf16x8*)(hbufb + (size_t)d * F1 + fg * 8) = o;
    }
}

// ---------------- fused GAT layer 2 ----------------
__global__ void gat2_fused(const int* __restrict__ degs, const int* __restrict__ srcs,
                           const float* __restrict__ el, const float* __restrict__ er,
                           const __bf16* __restrict__ feat2p, const float* __restrict__ b2,
                           float* __restrict__ out) {
    int wave = threadIdx.x >> 6;
    int lane = threadIdx.x & 63;
    int d = blockIdx.x * 4 + wave;
    if (d >= N_NODES) return;
    int off = d * STRIDE;
    int deg = degs[d];

    float er_d = er[d];
    int q  = lane >> 4;
    int cg = lane & 15;
    f32x2 accv[2];
    accv[0].x = 0.f; accv[0].y = 0.f; accv[1].x = 0.f; accv[1].y = 0.f;

    if (deg <= 64) {
        float sc = NEG_INF;
        int s0 = 0;
        if (lane < deg) {
            s0 = srcs[off + lane];
            sc = leaky(el[s0] + er_d);
        }
        float m = sc, l = (sc == NEG_INF) ? 0.f : 1.f;
        #pragma unroll
        for (int mask = 1; mask <= 32; mask <<= 1) {
            float m2 = __shfl_xor(m, mask, 64);
            float l2 = __shfl_xor(l, mask, 64);
            float mn = fmaxf(m, m2);
            float f1 = (m  == NEG_INF) ? 0.f : __expf(m - mn);
            float f2 = (m2 == NEG_INF) ? 0.f : __expf(m2 - mn);
            l = l * f1 + l2 * f2;
            m = mn;
        }
        float inv_l = 1.f / (l + 1e-9f);
        float alpha = (lane < deg) ? __expf(sc - m) * inv_l : 0.f;

        int nsub = (min(deg, 64) + 3) >> 2;
        for (int sub = 0; sub < nsub; ++sub) {
            int k = sub * 4 + q;
            float a  = __shfl(alpha, k, 64);
            int   se = __shfl(s0,    k, 64);
            uint2 p = *(const uint2*)(feat2p + (size_t)se * CLSP + cg * 4);
            f32x2 av; av.x = a; av.y = a;
            accv[0] += av * unpk(p.x);
            accv[1] += av * unpk(p.y);
        }
    } else {
        float m = NEG_INF, l = 0.f;
        for (int base = 0; base < deg; base += 64) {
            int e = base + lane;
            float sc = NEG_INF;
            if (e < deg) {
                int s = srcs[off + e];
                sc = leaky(el[s] + er_d);
            }
            float mn = fmaxf(m, sc);
            float f1 = (m  == NEG_INF) ? 0.f : __expf(m - mn);
            float f2 = (sc == NEG_INF) ? 0.f : __expf(sc - mn);
            l = l * f1 + f2;
            m = mn;
        }
        #pragma unroll
        for (int mask = 1; mask <= 32; mask <<= 1) {
            float m2 = __shfl_xor(m, mask, 64);
            float l2 = __shfl_xor(l, mask, 64);
            float mn = fmaxf(m, m2);
            float f1 = (m  == NEG_INF) ? 0.f : __expf(m - mn);
            float f2 = (m2 == NEG_INF) ? 0.f : __expf(m2 - mn);
            l = l * f1 + l2 * f2;
            m = mn;
        }
        float inv_l = 1.f / (l + 1e-9f);

        for (int base = 0; base < deg; base += 64) {
            int e = base + lane;
            float alpha = 0.f;
            int s = 0;
            if (e < deg) {
                s = srcs[off + e];
                float sc = leaky(el[s] + er_d);
                alpha = __expf(sc - m) * inv_l;
            }
            int kmax = min(64, deg - base);
            int nsub = (kmax + 3) >> 2;
            for (int sub = 0; sub < nsub; ++sub) {
                int k = sub * 4 + q;
                float a  = __shfl(alpha, k, 64);
                int   se = __shfl(s,     k, 64);
                uint2 p = *(const uint2*)(feat2p + (size_t)se * CLSP + cg * 4);
                f32x2 av; av.x = a; av.y = a;
                accv[0] += av * unpk(p.x);
                accv[1] += av * unpk(p.y);
            }
        }
    }

    float acc[4];
    acc[0] = accv[0].x; acc[1] = accv[0].y; acc[2] = accv[1].x; acc[3] = accv[1].y;
    #pragma unroll
    for (int i = 0; i < 4; ++i) {
        acc[i] += __shfl_xor(acc[i], 16, 64);
        acc[i] += __shfl_xor(acc[i], 32, 64);
    }
    if (lane < 10) {   // q==0, cg<10
        float4 o;
        o.x = acc[0] + b2[cg * 4 + 0];
        o.y = acc[1] + b2[cg * 4 + 1];
        o.z = acc[2] + b2[cg * 4 + 2];
        o.w = acc[3] + b2[cg * 4 + 3];
        *(float4*)(out + (size_t)d * CLS + cg * 4) = o;
    }
}

// ---------------- launch ----------------
extern "C" void kernel_launch(void* const* d_in, const int* in_sizes, int n_in,
                              void* d_out, int out_size, void* d_ws, size_t ws_size,
                              hipStream_t stream) {
    const float* features = (const float*)d_in[0];
    const int*   esrc     = (const int*)d_in[1];
    const int*   edst     = (const int*)d_in[2];
    const float* W1       = (const float*)d_in[3];
    const float* al1      = (const float*)d_in[4];
    const float* ar1      = (const float*)d_in[5];
    const float* b1       = (const float*)d_in[6];
    const float* W2       = (const float*)d_in[7];
    const float* al2      = (const float*)d_in[8];
    const float* ar2      = (const float*)d_in[9];
    const float* b2       = (const float*)d_in[10];
    float* out = (float*)d_out;

    float* ws = (float*)d_ws;
    float*  el1    = ws;                        // 400,000
    float*  er1    = ws + 400000;               // 400,000
    float*  el2    = ws + 800000;               // 50,000
    float*  er2    = ws + 850000;               // 50,000
    int*    cursor = (int*)(ws + 900000);       // 50,000
    int*    srcs   = (int*)(ws + 950000);       // 4,800,000 (padded CSR)
    __bf16* feat1b = (__bf16*)(ws + 5750000);   // 6,400,000 bf16 (3.2M floats)
    __bf16* hbufb  = (__bf16*)(ws + 8950000);   // 6,400,000 bf16
    __bf16* feat2p = (__bf16*)(ws + 12150000);  // 3,200,000 bf16 (1.6M floats)
    __bf16* w1t    = (__bf16*)(ws + 13750000);  // 16,384 bf16
    __bf16* w2t    = (__bf16*)(ws + 13760000);  // 8,192 bf16
    // total ~13.77M floats = 55 MB

    const int B = 256;
    const int BPS = (N_EDGES + 255) / 256;

    setup_kernel<<<(N_NODES + B - 1) / B, B, 0, stream>>>(W1, W2, w1t, w2t, cursor);
    scatter_kernel<<<SWEEPS * BPS, B, 0, stream>>>(esrc, edst, cursor, srcs);

    gemm1_mfma<<<(N_NODES + 63) / 64, 256, 0, stream>>>(features, w1t, al1, ar1,
                                                        feat1b, el1, er1);
    gat1_fused<<<(N_NODES + 3) / 4, B, 0, stream>>>(cursor, srcs, el1, er1, feat1b, b1, hbufb);

    gemm2_mfma<<<(N_NODES + 63) / 64, 256, 0, stream>>>(hbufb, w2t, al2, ar2,
                                                        feat2p, el2, er2);
    gat2_fused<<<(N_NODES + 3) / 4, B, 0, stream>>>(cursor, srcs, el2, er2, feat2p, b2, out);
}

// Round 9
// 269.137 us; speedup vs baseline: 1.2034x; 1.0144x over previous
//
#include <hip/hip_runtime.h>
#include <hip/hip_bf16.h>

#define N_NODES 50000
#define N_EDGES 800000
#define IN_F    128
#define HID     16
#define HEADS   8
#define F1      128   // HEADS*HID
#define CLS     40
#define CLSP    64    // padded bf16 feat2 stride
#define NEG     0.2f
#define NEG_INF (-__builtin_inff())
#define SWEEPS      8
#define SWEEP_RANGE 6250   // N_NODES / SWEEPS
#define STRIDE      96     // padded CSR slot count per node (P(deg>96) ~ 0)

typedef __bf16 bf16x8 __attribute__((ext_vector_type(8)));
typedef float  f32x4  __attribute__((ext_vector_type(4)));
typedef float  f32x2  __attribute__((ext_vector_type(2)));

__device__ __forceinline__ float leaky(float v) { return v >= 0.0f ? v : NEG * v; }
__device__ __forceinline__ f32x2 unpk(unsigned u) {
    f32x2 r;
    r.x = __uint_as_float(u << 16);
    r.y = __uint_as_float(u & 0xffff0000u);
    return r;
}

// ---------------- setup: zero cursor + weight transposes ----------------
__global__ void setup_kernel(const float* __restrict__ W1, const float* __restrict__ W2,
                             __bf16* __restrict__ w1t, __bf16* __restrict__ w2t,
                             int* __restrict__ cursor) {
    int i = blockIdx.x * blockDim.x + threadIdx.x;
    if (i < N_NODES) cursor[i] = 0;
    if (i < 128 * 128) {
        int n = i >> 7, k = i & 127;
        w1t[i] = (__bf16)W1[k * 128 + n];
    }
    if (i < CLSP * 128) {
        int n = i >> 7, k = i & 127;
        w2t[i] = (n < CLS) ? (__bf16)W2[k * CLS + n] : (__bf16)0.0f;
    }
}

// ---------------- swept scatter into padded CSR ----------------
__global__ void scatter_kernel(const int* __restrict__ src, const int* __restrict__ dst,
                               int* __restrict__ cursor, int* __restrict__ srcs_sorted) {
    const int BPS = (N_EDGES + 255) / 256;
    int sweep = blockIdx.x / BPS;
    int e = (blockIdx.x - sweep * BPS) * 256 + threadIdx.x;
    if (e >= N_EDGES) return;
    int d = dst[e];
    int lo = sweep * SWEEP_RANGE;
    if (d < lo || d >= lo + SWEEP_RANGE) return;
    int pos = d * STRIDE + atomicAdd(&cursor[d], 1);
    srcs_sorted[pos] = src[e];
}

// ---------------- GEMM1 + fused elr1 epilogue ----------------
__global__ __launch_bounds__(256) void gemm1_mfma(const float* __restrict__ A,
                                                  const __bf16* __restrict__ Wt,
                                                  const float* __restrict__ al1,
                                                  const float* __restrict__ ar1,
                                                  __bf16* __restrict__ outb,
                                                  float* __restrict__ el,
                                                  float* __restrict__ er) {
    int wave = threadIdx.x >> 6, lane = threadIdx.x & 63;
    int m0 = blockIdx.x * 64 + wave * 16;
    int c = lane & 15;
    int row = m0 + c;
    int rowc = row < N_NODES ? row : N_NODES - 1;
    int ko = (lane >> 4) * 8;

    f32x4 acc[8];
    #pragma unroll
    for (int t = 0; t < 8; ++t)
        #pragma unroll
        for (int r = 0; r < 4; ++r) acc[t][r] = 0.f;

    for (int ks = 0; ks < 128; ks += 32) {
        const float* ap = A + (size_t)rowc * 128 + ks + ko;
        float4 u = *(const float4*)ap;
        float4 v = *(const float4*)(ap + 4);
        bf16x8 a;
        a[0] = (__bf16)u.x; a[1] = (__bf16)u.y; a[2] = (__bf16)u.z; a[3] = (__bf16)u.w;
        a[4] = (__bf16)v.x; a[5] = (__bf16)v.y; a[6] = (__bf16)v.z; a[7] = (__bf16)v.w;
        #pragma unroll
        for (int t = 0; t < 8; ++t) {
            bf16x8 b = *(const bf16x8*)(Wt + (size_t)(t * 16 + c) * 128 + ks + ko);
            acc[t] = __builtin_amdgcn_mfma_f32_16x16x32_bf16(a, b, acc[t], 0, 0, 0);
        }
    }
    int rbase = m0 + (lane >> 4) * 4;
    #pragma unroll
    for (int t = 0; t < 8; ++t) {
        int gcol = t * 16 + c;
        #pragma unroll
        for (int r = 0; r < 4; ++r) {
            int grow = rbase + r;
            if (grow < N_NODES) outb[(size_t)grow * 128 + gcol] = (__bf16)acc[t][r];
        }
    }
    // fused elr1
    #pragma unroll
    for (int t = 0; t < 8; ++t) {
        float alv = al1[t * 16 + c];
        float arv = ar1[t * 16 + c];
        float pe[4], pr[4];
        #pragma unroll
        for (int r = 0; r < 4; ++r) { pe[r] = acc[t][r] * alv; pr[r] = acc[t][r] * arv; }
        #pragma unroll
        for (int mask = 1; mask <= 8; mask <<= 1) {
            #pragma unroll
            for (int r = 0; r < 4; ++r) {
                pe[r] += __shfl_xor(pe[r], mask, 64);
                pr[r] += __shfl_xor(pr[r], mask, 64);
            }
        }
        if (c == 0) {
            #pragma unroll
            for (int r = 0; r < 4; ++r) {
                int grow = rbase + r;
                if (grow < N_NODES) {
                    el[grow * 8 + t] = pe[r];
                    er[grow * 8 + t] = pr[r];
                }
            }
        }
    }
}

// ---------------- GEMM2 + fused elr2 epilogue ----------------
__global__ __launch_bounds__(256) void gemm2_mfma(const __bf16* __restrict__ A,
                                                  const __bf16* __restrict__ Wt,
                                                  const float* __restrict__ al2,
                                                  const float* __restrict__ ar2,
                                                  __bf16* __restrict__ out,
                                                  float* __restrict__ el,
                                                  float* __restrict__ er) {
    int wave = threadIdx.x >> 6, lane = threadIdx.x & 63;
    int m0 = blockIdx.x * 64 + wave * 16;
    int c = lane & 15;
    int row = m0 + c;
    int rowc = row < N_NODES ? row : N_NODES - 1;
    int ko = (lane >> 4) * 8;

    f32x4 acc[4];
    #pragma unroll
    for (int t = 0; t < 4; ++t)
        #pragma unroll
        for (int r = 0; r < 4; ++r) acc[t][r] = 0.f;

    for (int ks = 0; ks < 128; ks += 32) {
        bf16x8 a = *(const bf16x8*)(A + (size_t)rowc * 128 + ks + ko);
        #pragma unroll
        for (int t = 0; t < 4; ++t) {
            bf16x8 b = *(const bf16x8*)(Wt + (size_t)(t * 16 + c) * 128 + ks + ko);
            acc[t] = __builtin_amdgcn_mfma_f32_16x16x32_bf16(a, b, acc[t], 0, 0, 0);
        }
    }
    int rbase = m0 + (lane >> 4) * 4;
    #pragma unroll
    for (int t = 0; t < 4; ++t) {
        int gcol = t * 16 + c;
        #pragma unroll
        for (int r = 0; r < 4; ++r) {
            int grow = rbase + r;
            if (grow < N_NODES) out[(size_t)grow * CLSP + gcol] = (__bf16)acc[t][r];
        }
    }
    float pe[4] = {0.f, 0.f, 0.f, 0.f}, pr[4] = {0.f, 0.f, 0.f, 0.f};
    #pragma unroll
    for (int t = 0; t < 3; ++t) {
        int idx = t * 16 + c;
        float alv = (idx < CLS) ? al2[idx] : 0.f;
        float arv = (idx < CLS) ? ar2[idx] : 0.f;
        #pragma unroll
        for (int r = 0; r < 4; ++r) { pe[r] += acc[t][r] * alv; pr[r] += acc[t][r] * arv; }
    }
    #pragma unroll
    for (int mask = 1; mask <= 8; mask <<= 1) {
        #pragma unroll
        for (int r = 0; r < 4; ++r) {
            pe[r] += __shfl_xor(pe[r], mask, 64);
            pr[r] += __shfl_xor(pr[r], mask, 64);
        }
    }
    if (c == 0) {
        #pragma unroll
        for (int r = 0; r < 4; ++r) {
            int grow = rbase + r;
            if (grow < N_NODES) { el[grow] = pe[r]; er[grow] = pr[r]; }
        }
    }
}

// ---------------- fused GAT layer 1 (LDS-staged alpha/src) ----------------
// N_NODES % 4 == 0 -> every wave has a valid node; __syncthreads is safe.
__global__ __launch_bounds__(256) void gat1_fused(const int* __restrict__ degs,
                                                  const int* __restrict__ srcs,
                                                  const float* __restrict__ el,
                                                  const float* __restrict__ er,
                                                  const __bf16* __restrict__ feat1b,
                                                  const float* __restrict__ b1,
                                                  __bf16* __restrict__ hbufb) {
    __shared__ float a_lds[4][64 * 8];   // [wave][edge*8 + head]
    __shared__ int   s_lds[4][64];       // [wave][edge]
    int wave = threadIdx.x >> 6;
    int lane = threadIdx.x & 63;
    int d = blockIdx.x * 4 + wave;
    int off = d * STRIDE;
    int deg = degs[d];

    int h = lane & 7, slot = lane >> 3;
    int q = lane >> 4, fg = lane & 15, hd = fg >> 1;
    float er_d = er[d * 8 + h];

    f32x2 accv[4];
    #pragma unroll
    for (int j = 0; j < 4; ++j) { accv[j].x = 0.f; accv[j].y = 0.f; }

    bool fast = (deg <= 64);
    if (fast) {
        int nit = (deg + 7) >> 3;
        float sc[8];
        int sreg[8];
        float m = NEG_INF;
        #pragma unroll
        for (int it = 0; it < 8; ++it) {
            float v = NEG_INF;
            int e = it * 8 + slot;
            if (it < nit && e < deg) {
                sreg[it] = srcs[off + e];
                v = leaky(el[sreg[it] * 8 + h] + er_d);
            }
            sc[it] = v;
            m = fmaxf(m, v);
        }
        float l = 0.f;
        #pragma unroll
        for (int it = 0; it < 8; ++it)
            l += (sc[it] == NEG_INF) ? 0.f : __expf(sc[it] - m);
        #pragma unroll
        for (int mask = 8; mask <= 32; mask <<= 1) {
            float m2 = __shfl_xor(m, mask, 64);
            float l2 = __shfl_xor(l, mask, 64);
            float mn = fmaxf(m, m2);
            float f1 = (m  == NEG_INF) ? 0.f : __expf(m - mn);
            float f2 = (m2 == NEG_INF) ? 0.f : __expf(m2 - mn);
            l = l * f1 + l2 * f2;
            m = mn;
        }
        float inv_l = 1.f / (l + 1e-9f);
        // stage alpha + src into LDS
        #pragma unroll
        for (int it = 0; it < 8; ++it) {
            int e = it * 8 + slot;
            if (it < nit && e < deg) {
                a_lds[wave][e * 8 + h] = __expf(sc[it] - m) * inv_l;
                if (h == 0) s_lds[wave][e] = sreg[it];
            }
        }
    }
    __syncthreads();

    if (fast) {
        int ng = (deg + 3) >> 2;
        #pragma unroll 4
        for (int g = 0; g < ng; ++g) {
            int k = g * 4 + q;
            float a = 0.f;
            int se = 0;
            if (k < deg) {
                a = a_lds[wave][k * 8 + hd];
                se = s_lds[wave][k];
            }
            uint4 p = *(const uint4*)(feat1b + (size_t)se * F1 + fg * 8);
            f32x2 av; av.x = a; av.y = a;
            accv[0] += av * unpk(p.x);
            accv[1] += av * unpk(p.y);
            accv[2] += av * unpk(p.z);
            accv[3] += av * unpk(p.w);
        }
    } else {
        // slow path (deg > 64): recompute + shuffle broadcast, no LDS
        float m = NEG_INF, l = 0.f;
        for (int base = 0; base < deg; base += 8) {
            int e = base + slot;
            float v = NEG_INF;
            if (e < deg) {
                int s = srcs[off + e];
                v = leaky(el[s * 8 + h] + er_d);
            }
            float mn = fmaxf(m, v);
            float f1 = (m == NEG_INF) ? 0.f : __expf(m - mn);
            float f2 = (v == NEG_INF) ? 0.f : __expf(v - mn);
            l = l * f1 + f2;
            m = mn;
        }
        #pragma unroll
        for (int mask = 8; mask <= 32; mask <<= 1) {
            float m2 = __shfl_xor(m, mask, 64);
            float l2 = __shfl_xor(l, mask, 64);
            float mn = fmaxf(m, m2);
            float f1 = (m  == NEG_INF) ? 0.f : __expf(m - mn);
            float f2 = (m2 == NEG_INF) ? 0.f : __expf(m2 - mn);
            l = l * f1 + l2 * f2;
            m = mn;
        }
        float inv_l = 1.f / (l + 1e-9f);

        for (int base = 0; base < deg; base += 8) {
            int e = base + slot;
            float alpha = 0.f;
            int s = 0;
            if (e < deg) {
                s = srcs[off + e];
                float v = leaky(el[s * 8 + h] + er_d);
                alpha = __expf(v - m) * inv_l;
            }
            #pragma unroll
            for (int sub = 0; sub < 2; ++sub) {
                int k = sub * 4 + q;
                float a  = __shfl(alpha, k * 8 + hd, 64);
                int   se = __shfl(s,     k * 8,      64);
                uint4 p = *(const uint4*)(feat1b + (size_t)se * F1 + fg * 8);
                f32x2 av; av.x = a; av.y = a;
                accv[0] += av * unpk(p.x);
                accv[1] += av * unpk(p.y);
                accv[2] += av * unpk(p.z);
                accv[3] += av * unpk(p.w);
            }
        }
    }

    float acc[8];
    #pragma unroll
    for (int j = 0; j < 4; ++j) { acc[2 * j] = accv[j].x; acc[2 * j + 1] = accv[j].y; }
    #pragma unroll
    for (int i = 0; i < 8; ++i) {
        acc[i] += __shfl_xor(acc[i], 16, 64);
        acc[i] += __shfl_xor(acc[i], 32, 64);
    }
    if (q == 0) {
        bf16x8 o;
        #pragma unroll
        for (int i = 0; i < 8; ++i) {
            float v = acc[i] + b1[fg * 8 + i];
            v = v > 0.f ? v : expm1f(v);
            o[i] = (__bf16)v;
        }
        *(bf16x8*)(hbufb + (size_t)d * F1 + fg * 8) = o;
    }
}

// ---------------- fused GAT layer 2 (LDS-staged alpha/src) ----------------
__global__ __launch_bounds__(256) void gat2_fused(const int* __restrict__ degs,
                                                  const int* __restrict__ srcs,
                                                  const float* __restrict__ el,
                                                  const float* __restrict__ er,
                                                  const __bf16* __restrict__ feat2p,
                                                  const float* __restrict__ b2,
                                                  float* __restrict__ out) {
    __shared__ float a_lds[4][64];
    __shared__ int   s_lds[4][64];
    int wave = threadIdx.x >> 6;
    int lane = threadIdx.x & 63;
    int d = blockIdx.x * 4 + wave;
    int off = d * STRIDE;
    int deg = degs[d];

    float er_d = er[d];
    int q  = lane >> 4;
    int cg = lane & 15;
    f32x2 accv[2];
    accv[0].x = 0.f; accv[0].y = 0.f; accv[1].x = 0.f; accv[1].y = 0.f;

    bool fast = (deg <= 64);
    if (fast) {
        float sc = NEG_INF;
        int s0 = 0;
        if (lane < deg) {
            s0 = srcs[off + lane];
            sc = leaky(el[s0] + er_d);
        }
        float m = sc, l = (sc == NEG_INF) ? 0.f : 1.f;
        #pragma unroll
        for (int mask = 1; mask <= 32; mask <<= 1) {
            float m2 = __shfl_xor(m, mask, 64);
            float l2 = __shfl_xor(l, mask, 64);
            float mn = fmaxf(m, m2);
            float f1 = (m  == NEG_INF) ? 0.f : __expf(m - mn);
            float f2 = (m2 == NEG_INF) ? 0.f : __expf(m2 - mn);
            l = l * f1 + l2 * f2;
            m = mn;
        }
        float inv_l = 1.f / (l + 1e-9f);
        if (lane < deg) {
            a_lds[wave][lane] = __expf(sc - m) * inv_l;
            s_lds[wave][lane] = s0;
        }
    }
    __syncthreads();

    if (fast) {
        int ng = (deg + 3) >> 2;
        #pragma unroll 4
        for (int g = 0; g < ng; ++g) {
            int k = g * 4 + q;
            float a = 0.f;
            int se = 0;
            if (k < deg) {
                a = a_lds[wave][k];
                se = s_lds[wave][k];
            }
            uint2 p = *(const uint2*)(feat2p + (size_t)se * CLSP + cg * 4);
            f32x2 av; av.x = a; av.y = a;
            accv[0] += av * unpk(p.x);
            accv[1] += av * unpk(p.y);
        }
    } else {
        float m = NEG_INF, l = 0.f;
        for (int base = 0; base < deg; base += 64) {
            int e = base + lane;
            float sc = NEG_INF;
            if (e < deg) {
                int s = srcs[off + e];
                sc = leaky(el[s] + er_d);
            }
            float mn = fmaxf(m, sc);
            float f1 = (m  == NEG_INF) ? 0.f : __expf(m - mn);
            float f2 = (sc == NEG_INF) ? 0.f : __expf(sc - mn);
            l = l * f1 + f2;
            m = mn;
        }
        #pragma unroll
        for (int mask = 1; mask <= 32; mask <<= 1) {
            float m2 = __shfl_xor(m, mask, 64);
            float l2 = __shfl_xor(l, mask, 64);
            float mn = fmaxf(m, m2);
            float f1 = (m  == NEG_INF) ? 0.f : __expf(m - mn);
            float f2 = (m2 == NEG_INF) ? 0.f : __expf(m2 - mn);
            l = l * f1 + l2 * f2;
            m = mn;
        }
        float inv_l = 1.f / (l + 1e-9f);

        for (int base = 0; base < deg; base += 64) {
            int e = base + lane;
            float alpha = 0.f;
            int s = 0;
            if (e < deg) {
                s = srcs[off + e];
                float sc = leaky(el[s] + er_d);
                alpha = __expf(sc - m) * inv_l;
            }
            int kmax = min(64, deg - base);
            int nsub = (kmax + 3) >> 2;
            for (int sub = 0; sub < nsub; ++sub) {
                int k = sub * 4 + q;
                float a  = __shfl(alpha, k, 64);
                int   se = __shfl(s,     k, 64);
                uint2 p = *(const uint2*)(feat2p + (size_t)se * CLSP + cg * 4);
                f32x2 av; av.x = a; av.y = a;
                accv[0] += av * unpk(p.x);
                accv[1] += av * unpk(p.y);
            }
        }
    }

    float acc[4];
    acc[0] = accv[0].x; acc[1] = accv[0].y; acc[2] = accv[1].x; acc[3] = accv[1].y;
    #pragma unroll
    for (int i = 0; i < 4; ++i) {
        acc[i] += __shfl_xor(acc[i], 16, 64);
        acc[i] += __shfl_xor(acc[i], 32, 64);
    }
    if (lane < 10) {   // q==0, cg<10
        float4 o;
        o.x = acc[0] + b2[cg * 4 + 0];
        o.y = acc[1] + b2[cg * 4 + 1];
        o.z = acc[2] + b2[cg * 4 + 2];
        o.w = acc[3] + b2[cg * 4 + 3];
        *(float4*)(out + (size_t)d * CLS + cg * 4) = o;
    }
}

// ---------------- launch ----------------
extern "C" void kernel_launch(void* const* d_in, const int* in_sizes, int n_in,
                              void* d_out, int out_size, void* d_ws, size_t ws_size,
                              hipStream_t stream) {
    const float* features = (const float*)d_in[0];
    const int*   esrc     = (const int*)d_in[1];
    const int*   edst     = (const int*)d_in[2];
    const float* W1       = (const float*)d_in[3];
    const float* al1      = (const float*)d_in[4];
    const float* ar1      = (const float*)d_in[5];
    const float* b1       = (const float*)d_in[6];
    const float* W2       = (const float*)d_in[7];
    const float* al2      = (const float*)d_in[8];
    const float* ar2      = (const float*)d_in[9];
    const float* b2       = (const float*)d_in[10];
    float* out = (float*)d_out;

    float* ws = (float*)d_ws;
    float*  el1    = ws;                        // 400,000
    float*  er1    = ws + 400000;               // 400,000
    float*  el2    = ws + 800000;               // 50,000
    float*  er2    = ws + 850000;               // 50,000
    int*    cursor = (int*)(ws + 900000);       // 50,000
    int*    srcs   = (int*)(ws + 950000);       // 4,800,000 (padded CSR)
    __bf16* feat1b = (__bf16*)(ws + 5750000);   // 6,400,000 bf16 (3.2M floats)
    __bf16* hbufb  = (__bf16*)(ws + 8950000);   // 6,400,000 bf16
    __bf16* feat2p = (__bf16*)(ws + 12150000);  // 3,200,000 bf16 (1.6M floats)
    __bf16* w1t    = (__bf16*)(ws + 13750000);  // 16,384 bf16
    __bf16* w2t    = (__bf16*)(ws + 13760000);  // 8,192 bf16
    // total ~13.77M floats = 55 MB

    const int B = 256;
    const int BPS = (N_EDGES + 255) / 256;

    setup_kernel<<<(N_NODES + B - 1) / B, B, 0, stream>>>(W1, W2, w1t, w2t, cursor);
    scatter_kernel<<<SWEEPS * BPS, B, 0, stream>>>(esrc, edst, cursor, srcs);

    gemm1_mfma<<<(N_NODES + 63) / 64, 256, 0, stream>>>(features, w1t, al1, ar1,
                                                        feat1b, el1, er1);
    gat1_fused<<<N_NODES / 4, B, 0, stream>>>(cursor, srcs, el1, er1, feat1b, b1, hbufb);

    gemm2_mfma<<<(N_NODES + 63) / 64, 256, 0, stream>>>(hbufb, w2t, al2, ar2,
                                                        feat2p, el2, er2);
    gat2_fused<<<N_NODES / 4, B, 0, stream>>>(cursor, srcs, el2, er2, feat2p, b2, out);
}